// Round 5
// baseline (231.148 us; speedup 1.0000x reference)
//
#include <hip/hip_runtime.h>

typedef unsigned int uint;
typedef unsigned short ushort;
typedef __attribute__((ext_vector_type(8))) short bf16x8;
typedef __attribute__((ext_vector_type(4))) float f32x4;

#define BB 16
#define CC 256
#define II 128
#define NN 2048
#define BN_EPS 1e-5f

// ---- float workspace offsets (all write-once, no zero-init) ----
#define OFF_GPART 0            // [8][16][256][256] = 8,388,608
#define OFF_SPART 8388608      // [8][16][256]      = 32,768
#define OFF_CP    8421376      // [16][256]         = 4,096
#define OFF_STATP 8425472      // [256 slots][512]  = 131,072
#define OFF_STAT2 8556544      // [512]
#define OFF_PT    8557056      // [256]
#define OFF_R1    8557312      // [256]
#define OFF_WGB   8557568      // [256]
#define OFF_ALPHA 8557824      // [256] (only [0] used)
#define OFF_L1    8558080      // [16][256]
#define OFF_R2    8562176      // [16][256]
#define OFF_FEND  8566272
// ---- ushort offsets relative to (ushort*)(wsf + OFF_FEND) ----
#define UGRAM 0                // [16][256][256] bf16
#define UE    1048576          // [256][256]
#define UFT   1114112          // [256][256]
#define USBF  1179648          // [16][256][256]
#define UXT   2228224          // [16][2048][256]
#define UZ    10616832         // [16][256][2048]

static __device__ __forceinline__ ushort f2bf(float f) {
    uint u = __float_as_uint(f);
    return (ushort)((u + 0x7FFFu + ((u >> 16) & 1u)) >> 16);
}
static __device__ __forceinline__ uint pack2(float a, float b) {
    return (uint)f2bf(a) | ((uint)f2bf(b) << 16);
}
static __device__ __forceinline__ float bflo(uint w) { return __uint_as_float(w << 16); }
static __device__ __forceinline__ float bfhi(uint w) { return __uint_as_float(w & 0xFFFF0000u); }

#define MICRO_FMA(av, bv) \
    acc[0][0] += av.x * bv.x; acc[0][1] += av.x * bv.y; acc[0][2] += av.x * bv.z; acc[0][3] += av.x * bv.w; \
    acc[1][0] += av.y * bv.x; acc[1][1] += av.y * bv.y; acc[1][2] += av.y * bv.z; acc[1][3] += av.y * bv.w; \
    acc[2][0] += av.z * bv.x; acc[2][1] += av.z * bv.y; acc[2][2] += av.z * bv.z; acc[2][3] += av.z * bv.w; \
    acc[3][0] += av.w * bv.x; acc[3][1] += av.w * bv.y; acc[3][2] += av.w * bv.z; acc[3][3] += av.w * bv.w;

// ===========================================================================
// D1 mega1: blocks [0,512): Gram partials (diag-dedup, diag blocks emit xT)
//           blocks [512,545): weight precompute (E, FT, pt/r1/wgb/alpha)
// ===========================================================================
__global__ __launch_bounds__(256) void mega1(
    const float* __restrict__ x,
    const float* __restrict__ Ww, const float* __restrict__ Gw,
    const float* __restrict__ Pw, const float* __restrict__ Tw,
    const float* __restrict__ gb, const float* __restrict__ pb, const float* __restrict__ tb,
    float* __restrict__ gpart, float* __restrict__ sPart, ushort* __restrict__ xT,
    ushort* __restrict__ EBF, ushort* __restrict__ FT,
    float* __restrict__ pt, float* __restrict__ r1, float* __restrict__ wgb,
    float* __restrict__ alpha)
{
    __shared__ __align__(16) char smem[20480];
    const int bid = blockIdx.x;
    const int t = threadIdx.x;

    if (bid < 512) {
        // ---------------- Gram ----------------
        ushort (*As)[40] = (ushort(*)[40])smem;
        ushort (*Bs)[40] = (ushort(*)[40])(smem + 10240);
        const int jt = bid & 1, it = (bid >> 1) & 1;
        const int z = bid >> 2;               // 0..127
        const int b = z >> 3, kc = z & 7;
        const int iBase = it * 128, jBase = jt * 128;
        const bool diag = (it == jt);
        const int arow = t >> 1, ah = t & 1;
        const float* aSrc = x + ((size_t)(b * CC + iBase + arow)) * NN + kc * 256 + ah * 16;
        const float* bSrc = x + ((size_t)(b * CC + jBase + arow)) * NN + kc * 256 + ah * 16;
        const int lane = t & 63, wid = t >> 6;
        const int mb = (wid >> 1) * 64, nb = (wid & 1) * 64;
        const int lm = lane & 15, q = lane >> 4;
        f32x4 acc[4][4] = {};
        float ssum = 0.f;

        for (int it16 = 0; it16 < 8; ++it16) {
            const float4* ap = (const float4*)(aSrc + it16 * 32);
            float4 a0 = ap[0], a1 = ap[1], a2 = ap[2], a3 = ap[3];
            uint4 pa0 = { pack2(a0.x,a0.y), pack2(a0.z,a0.w), pack2(a1.x,a1.y), pack2(a1.z,a1.w) };
            uint4 pa1 = { pack2(a2.x,a2.y), pack2(a2.z,a2.w), pack2(a3.x,a3.y), pack2(a3.z,a3.w) };
            *(uint4*)&As[arow][ah * 16]     = pa0;
            *(uint4*)&As[arow][ah * 16 + 8] = pa1;
            if (!diag) {
                const float4* bp = (const float4*)(bSrc + it16 * 32);
                float4 b0 = bp[0], b1 = bp[1], b2 = bp[2], b3 = bp[3];
                uint4 pb0 = { pack2(b0.x,b0.y), pack2(b0.z,b0.w), pack2(b1.x,b1.y), pack2(b1.z,b1.w) };
                uint4 pb1 = { pack2(b2.x,b2.y), pack2(b2.z,b2.w), pack2(b3.x,b3.y), pack2(b3.z,b3.w) };
                *(uint4*)&Bs[arow][ah * 16]     = pb0;
                *(uint4*)&Bs[arow][ah * 16 + 8] = pb1;
            }
            if (jt == 0) {
                ssum += a0.x+a0.y+a0.z+a0.w + a1.x+a1.y+a1.z+a1.w
                      + a2.x+a2.y+a2.z+a2.w + a3.x+a3.y+a3.z+a3.w;
            }
            __syncthreads();
            const ushort (*Bsel)[40] = diag ? (const ushort(*)[40])As : (const ushort(*)[40])Bs;
            bf16x8 af[4], bf[4];
            #pragma unroll
            for (int mt = 0; mt < 4; ++mt)
                af[mt] = *(const bf16x8*)&As[mb + mt * 16 + lm][q * 8];
            #pragma unroll
            for (int nt = 0; nt < 4; ++nt)
                bf[nt] = *(const bf16x8*)&Bsel[nb + nt * 16 + lm][q * 8];
            #pragma unroll
            for (int mt = 0; mt < 4; ++mt)
                #pragma unroll
                for (int nt = 0; nt < 4; ++nt)
                    acc[mt][nt] = __builtin_amdgcn_mfma_f32_16x16x32_bf16(af[mt], bf[nt], acc[mt][nt], 0, 0, 0);
            if (diag) {
                // emit xT tile from As: As[c 128][n 32] -> xT[b][n][c]
                const int n_l = t & 31, cg = t >> 5;     // 8 groups x 16 channels
                uint qv[8];
                #pragma unroll
                for (int i2 = 0; i2 < 8; ++i2) {
                    ushort lo = As[cg * 16 + 2*i2][n_l];
                    ushort hi = As[cg * 16 + 2*i2 + 1][n_l];
                    qv[i2] = (uint)lo | ((uint)hi << 16);
                }
                const int ng = kc * 256 + it16 * 32 + n_l;
                uint4* op = (uint4*)(xT + ((size_t)(b * NN + ng)) * CC + iBase + cg * 16);
                op[0] = make_uint4(qv[0], qv[1], qv[2], qv[3]);
                op[1] = make_uint4(qv[4], qv[5], qv[6], qv[7]);
            }
            __syncthreads();
        }
        float* gp = gpart + ((size_t)kc * BB + b) * CC * CC;
        #pragma unroll
        for (int mt = 0; mt < 4; ++mt)
            #pragma unroll
            for (int nt = 0; nt < 4; ++nt)
                #pragma unroll
                for (int r = 0; r < 4; ++r) {
                    const int gi = iBase + mb + mt * 16 + q * 4 + r;
                    const int gj = jBase + nb + nt * 16 + lm;
                    gp[(size_t)gi * CC + gj] = acc[mt][nt][r];
                }
        if (jt == 0) {
            const float so = __shfl_xor(ssum, 1);
            if ((t & 1) == 0)
                sPart[((size_t)kc * BB + b) * CC + iBase + arow] = ssum + so;
        }
        return;
    }

    // ---------------- w1 ----------------
    const int bz = bid - 512;
    if (bz == 32) {
        float ptv = 0.f, r1v = 0.f, wgbv = 0.f;
        for (int d = 0; d < II; ++d) {
            ptv  += Pw[(size_t)d * CC + t] * tb[d];
            r1v  += Tw[(size_t)d * CC + t] * pb[d];
            wgbv += Ww[(size_t)t * II + d] * gb[d];
        }
        pt[t] = ptv; r1[t] = r1v; wgb[t] = wgbv;
        if (t == 0) {
            float al = 0.f;
            for (int d = 0; d < II; ++d) al += pb[d] * tb[d];
            alpha[0] = al;
        }
        return;
    }
    float (*As)[68] = (float(*)[68])smem;
    float (*Bs)[68] = (float(*)[68])(smem + 8704);
    const int a_r = t >> 2, a_k = (t & 3) * 8;
    const int b_n = t & 63, b_k = t >> 6;
    const int ty = t >> 4, tx = t & 15;
    float acc[4][4] = {};
    if (bz < 16) {
        // E[c][i] = sum_e Ww[c][e]*Gw[e][i]
        const int cBase = (bz >> 2) * 64, iBase = (bz & 3) * 64;
        const float* ap0 = Ww + (size_t)(cBase + a_r) * II + a_k;
        const float* bp0 = Gw + iBase + b_n;
        for (int k0 = 0; k0 < II; k0 += 32) {
            #pragma unroll
            for (int j = 0; j < 8; ++j) As[a_k + j][a_r] = ap0[k0 + j];
            #pragma unroll
            for (int kk = 0; kk < 8; ++kk) {
                const int k = b_k + kk * 4;
                Bs[k][b_n] = bp0[(size_t)(k0 + k) * CC];
            }
            __syncthreads();
            #pragma unroll
            for (int k = 0; k < 32; ++k) {
                const float4 av = *(const float4*)&As[k][ty * 4];
                const float4 bv = *(const float4*)&Bs[k][tx * 4];
                MICRO_FMA(av, bv)
            }
            __syncthreads();
        }
        #pragma unroll
        for (int ii = 0; ii < 4; ++ii) {
            uint2 o = { pack2(acc[ii][0], acc[ii][1]), pack2(acc[ii][2], acc[ii][3]) };
            *(uint2*)&EBF[(size_t)(cBase + ty * 4 + ii) * CC + iBase + tx * 4] = o;
        }
    } else {
        // FT[j][k] = (1/N) * sum_d Tw[d][j]*Pw[d][k]
        const int zz = bz - 16;
        const int jBase = (zz >> 2) * 64, kBase = (zz & 3) * 64;
        const float* ap0 = Tw + jBase + b_n;
        const float* bp0 = Pw + kBase + b_n;
        for (int k0 = 0; k0 < II; k0 += 32) {
            #pragma unroll
            for (int kk = 0; kk < 8; ++kk) {
                const int k = b_k + kk * 4;
                As[k][b_n] = ap0[(size_t)(k0 + k) * CC];
                Bs[k][b_n] = bp0[(size_t)(k0 + k) * CC];
            }
            __syncthreads();
            #pragma unroll
            for (int k = 0; k < 32; ++k) {
                const float4 av = *(const float4*)&As[k][ty * 4];
                const float4 bv = *(const float4*)&Bs[k][tx * 4];
                MICRO_FMA(av, bv)
            }
            __syncthreads();
        }
        const float sc = 1.0f / (float)NN;
        #pragma unroll
        for (int ii = 0; ii < 4; ++ii) {
            uint2 o = { pack2(acc[ii][0]*sc, acc[ii][1]*sc), pack2(acc[ii][2]*sc, acc[ii][3]*sc) };
            *(uint2*)&FT[(size_t)(jBase + ty * 4 + ii) * CC + kBase + tx * 4] = o;
        }
    }
}

// ===========================================================================
// D2 mega2: blocks [0,1024): reduce 8 Gram partials -> GramBF
//           blocks [1024,1040): u-kernel (cprime, L1, R2) with coalesced Gpt
// ===========================================================================
__global__ __launch_bounds__(256) void mega2(
    const float* __restrict__ gpart, const float* __restrict__ sPart,
    const ushort* __restrict__ EBF, const ushort* __restrict__ FT,
    const float* __restrict__ pt, const float* __restrict__ r1,
    const float* __restrict__ wgb, const float* __restrict__ alpha,
    ushort* __restrict__ GramBF,
    float* __restrict__ cprime, float* __restrict__ L1, float* __restrict__ R2)
{
    const int bid = blockIdx.x;
    const int t = threadIdx.x;
    if (bid < 1024) {
        const int i = bid * 256 + t;               // float4 idx, 0..262143
        const size_t S = (size_t)BB * CC * CC / 4;
        const float4* p = (const float4*)gpart;
        float4 o = { 0.f, 0.f, 0.f, 0.f };
        #pragma unroll
        for (int k = 0; k < 8; ++k) {
            float4 v = p[i + (size_t)k * S];
            o.x += v.x; o.y += v.y; o.z += v.z; o.w += v.w;
        }
        uint2 pk = { pack2(o.x, o.y), pack2(o.z, o.w) };
        ((uint2*)GramBF)[i] = pk;
        return;
    }
    const int b = bid - 1024;
    __shared__ __align__(16) float sL[256], ptL[256], GptL[256], red[256];
    {
        float s = 0.f;
        #pragma unroll
        for (int kc = 0; kc < 8; ++kc) s += sPart[((size_t)kc * BB + b) * CC + t];
        sL[t] = s;
        ptL[t] = pt[t];
    }
    __syncthreads();
    red[t] = sL[t] * ptL[t];
    __syncthreads();
    for (int s = 128; s > 0; s >>= 1) {
        if (t < s) red[t] += red[t + s];
        __syncthreads();
    }
    const float spt = red[0];
    // Gpt: one wave per row, coalesced float4 reads of fp32 partials
    const int lane = t & 63, wv = t >> 6;
    {
        const float4 pt4 = *(const float4*)&ptL[lane * 4];
        for (int r = wv; r < 256; r += 4) {
            float a = 0.f;
            #pragma unroll
            for (int kc = 0; kc < 8; ++kc) {
                const float4 g = *(const float4*)&gpart[(((size_t)kc * BB + b) * CC + r) * CC + lane * 4];
                a += g.x * pt4.x + g.y * pt4.y + g.z * pt4.z + g.w * pt4.w;
            }
            #pragma unroll
            for (int m = 32; m > 0; m >>= 1) a += __shfl_xor(a, m);
            if (lane == 0) GptL[r] = a;
        }
    }
    __syncthreads();
    float es = 0.f, eg = 0.f;
    {
        const uint4* ep = (const uint4*)(EBF + (size_t)t * CC);
        #pragma unroll 4
        for (int kk = 0; kk < 32; ++kk) {
            uint4 v = ep[kk]; const int k = kk * 8;
            float e0=bflo(v.x),e1=bfhi(v.x),e2=bflo(v.y),e3=bfhi(v.y);
            float e4=bflo(v.z),e5=bfhi(v.z),e6=bflo(v.w),e7=bfhi(v.w);
            es += e0*sL[k]+e1*sL[k+1]+e2*sL[k+2]+e3*sL[k+3]+e4*sL[k+4]+e5*sL[k+5]+e6*sL[k+6]+e7*sL[k+7];
            eg += e0*GptL[k]+e1*GptL[k+1]+e2*GptL[k+2]+e3*GptL[k+3]+e4*GptL[k+4]+e5*GptL[k+5]+e6*GptL[k+6]+e7*GptL[k+7];
        }
    }
    float r2 = 0.f;
    {
        const uint4* fp = (const uint4*)(FT + (size_t)t * CC);
        #pragma unroll 4
        for (int kk = 0; kk < 32; ++kk) {
            uint4 v = fp[kk]; const int k = kk * 8;
            r2 += bflo(v.x)*sL[k]   + bfhi(v.x)*sL[k+1] + bflo(v.y)*sL[k+2] + bfhi(v.y)*sL[k+3]
                + bflo(v.z)*sL[k+4] + bfhi(v.z)*sL[k+5] + bflo(v.w)*sL[k+6] + bfhi(v.w)*sL[k+7];
        }
    }
    const float al = alpha[0];
    const float wg = wgb[t];
    cprime[b * CC + t] = (eg + al * es + spt * wg) / (float)NN + al * wg;
    L1[b * CC + t] = es / (float)NN;
    R2[b * CC + t] = r2 + r1[t];
}

// ===========================================================================
// D3 sfused: per block (b, c-tile, j-tile):
//   stage1: Q[c][k] = sum_i E[c][i] * Gram_b[k][i]  -> LDS (bf16, 2 halves)
//   stage2: S[c][j] = sum_k Q[c][k] * FT[j][k] + rank-1  -> Sbf
// ===========================================================================
__global__ __launch_bounds__(256) void sfused(
    const ushort* __restrict__ EBF, const ushort* __restrict__ GramBF,
    const ushort* __restrict__ FT,
    const float* __restrict__ r1, const float* __restrict__ R2,
    const float* __restrict__ L1, const float* __restrict__ wgb,
    ushort* __restrict__ Sbf)
{
    __shared__ ushort As[128][40];
    __shared__ ushort Bs[128][40];
    __shared__ ushort Qs[128][264];
    const int t = threadIdx.x;
    const int b = blockIdx.x >> 2;
    const int ct = (blockIdx.x >> 1) & 1, jt = blockIdx.x & 1;
    const int cBase = ct * 128, jBase = jt * 128;
    const int arow = t >> 1, ah = t & 1;
    const int lane = t & 63, wid = t >> 6;
    const int mb = (wid >> 1) * 64, nb = (wid & 1) * 64;
    const int lm = lane & 15, q = lane >> 4;
    const ushort* aSrc = EBF + (size_t)(cBase + arow) * CC + ah * 16;

    #pragma unroll
    for (int half = 0; half < 2; ++half) {
        const ushort* bSrc = GramBF + ((size_t)b * CC + half * 128 + arow) * CC + ah * 16;
        f32x4 acc[4][4] = {};
        for (int k0 = 0; k0 < CC; k0 += 32) {
            *(uint4*)&As[arow][ah * 16]     = ((const uint4*)(aSrc + k0))[0];
            *(uint4*)&As[arow][ah * 16 + 8] = ((const uint4*)(aSrc + k0))[1];
            *(uint4*)&Bs[arow][ah * 16]     = ((const uint4*)(bSrc + k0))[0];
            *(uint4*)&Bs[arow][ah * 16 + 8] = ((const uint4*)(bSrc + k0))[1];
            __syncthreads();
            bf16x8 af[4], bf[4];
            #pragma unroll
            for (int mt = 0; mt < 4; ++mt)
                af[mt] = *(const bf16x8*)&As[mb + mt * 16 + lm][q * 8];
            #pragma unroll
            for (int nt = 0; nt < 4; ++nt)
                bf[nt] = *(const bf16x8*)&Bs[nb + nt * 16 + lm][q * 8];
            #pragma unroll
            for (int mt = 0; mt < 4; ++mt)
                #pragma unroll
                for (int nt = 0; nt < 4; ++nt)
                    acc[mt][nt] = __builtin_amdgcn_mfma_f32_16x16x32_bf16(af[mt], bf[nt], acc[mt][nt], 0, 0, 0);
            __syncthreads();
        }
        #pragma unroll
        for (int mt = 0; mt < 4; ++mt)
            #pragma unroll
            for (int nt = 0; nt < 4; ++nt)
                #pragma unroll
                for (int r = 0; r < 4; ++r)
                    Qs[mb + mt * 16 + q * 4 + r][half * 128 + nb + nt * 16 + lm] = f2bf(acc[mt][nt][r]);
        __syncthreads();
    }
    // stage 2
    f32x4 acc[4][4] = {};
    const ushort* fSrc = FT + (size_t)(jBase + arow) * CC + ah * 16;
    for (int k0 = 0; k0 < CC; k0 += 32) {
        *(uint4*)&Bs[arow][ah * 16]     = ((const uint4*)(fSrc + k0))[0];
        *(uint4*)&Bs[arow][ah * 16 + 8] = ((const uint4*)(fSrc + k0))[1];
        __syncthreads();
        bf16x8 af[4], bf[4];
        #pragma unroll
        for (int mt = 0; mt < 4; ++mt)
            af[mt] = *(const bf16x8*)&Qs[mb + mt * 16 + lm][k0 + q * 8];
        #pragma unroll
        for (int nt = 0; nt < 4; ++nt)
            bf[nt] = *(const bf16x8*)&Bs[nb + nt * 16 + lm][q * 8];
        #pragma unroll
        for (int mt = 0; mt < 4; ++mt)
            #pragma unroll
            for (int nt = 0; nt < 4; ++nt)
                acc[mt][nt] = __builtin_amdgcn_mfma_f32_16x16x32_bf16(af[mt], bf[nt], acc[mt][nt], 0, 0, 0);
        __syncthreads();
    }
    float r1v[4], R2v[4];
    #pragma unroll
    for (int nt = 0; nt < 4; ++nt) {
        const int j = jBase + nb + nt * 16 + lm;
        r1v[nt] = r1[j];
        R2v[nt] = R2[b * CC + j];
    }
    ushort* dst = Sbf + (size_t)b * CC * CC;
    #pragma unroll
    for (int mt = 0; mt < 4; ++mt)
        #pragma unroll
        for (int r = 0; r < 4; ++r) {
            const int c = cBase + mb + mt * 16 + q * 4 + r;
            const float l1v = L1[b * CC + c], wgv = wgb[c];
            #pragma unroll
            for (int nt = 0; nt < 4; ++nt) {
                const int j = jBase + nb + nt * 16 + lm;
                dst[(size_t)c * CC + j] = f2bf(acc[mt][nt][r] + l1v * r1v[nt] + wgv * R2v[nt]);
            }
        }
}

// ===========================================================================
// D4: z_b = S_b @ x_b + c' 1^T (bf16 MFMA) -> zbf; per-block BN partials
// ===========================================================================
__global__ __launch_bounds__(256) void z_mfma(
    const ushort* __restrict__ Sbf, const ushort* __restrict__ xT,
    const float* __restrict__ cprime, ushort* __restrict__ zbf,
    float* __restrict__ statsPart)
{
    __shared__ ushort As[128][40];
    __shared__ ushort Bs[128][40];
    __shared__ float cpL[128];
    __shared__ float sSum[2][128], sSq[2][128];
    const int t = threadIdx.x;
    const int n0 = blockIdx.x * 128, ct = blockIdx.y * 128, b = blockIdx.z;
    const int arow = t >> 1, ah = t & 1;
    const ushort* aSrc = Sbf + ((size_t)(b * CC + ct + arow)) * CC + ah * 16;
    const ushort* bSrc = xT + ((size_t)(b * NN + n0 + arow)) * CC + ah * 16;
    const int lane = t & 63, wid = t >> 6;
    const int mb = (wid >> 1) * 64, nb = (wid & 1) * 64;
    const int lm = lane & 15, q = lane >> 4;
    f32x4 acc[4][4] = {};

    if (t < 128) cpL[t] = cprime[b * CC + ct + t];

    for (int k0 = 0; k0 < CC; k0 += 32) {
        *(uint4*)&As[arow][ah * 16]     = ((const uint4*)(aSrc + k0))[0];
        *(uint4*)&As[arow][ah * 16 + 8] = ((const uint4*)(aSrc + k0))[1];
        *(uint4*)&Bs[arow][ah * 16]     = ((const uint4*)(bSrc + k0))[0];
        *(uint4*)&Bs[arow][ah * 16 + 8] = ((const uint4*)(bSrc + k0))[1];
        __syncthreads();
        bf16x8 af[4], bf[4];
        #pragma unroll
        for (int mt = 0; mt < 4; ++mt)
            af[mt] = *(const bf16x8*)&As[mb + mt * 16 + lm][q * 8];
        #pragma unroll
        for (int nt = 0; nt < 4; ++nt)
            bf[nt] = *(const bf16x8*)&Bs[nb + nt * 16 + lm][q * 8];
        #pragma unroll
        for (int mt = 0; mt < 4; ++mt)
            #pragma unroll
            for (int nt = 0; nt < 4; ++nt)
                acc[mt][nt] = __builtin_amdgcn_mfma_f32_16x16x32_bf16(af[mt], bf[nt], acc[mt][nt], 0, 0, 0);
        __syncthreads();
    }
    const int nbw = wid & 1;
    #pragma unroll
    for (int mt = 0; mt < 4; ++mt) {
        #pragma unroll
        for (int r = 0; r < 4; ++r) {
            const int cl = mb + mt * 16 + q * 4 + r;
            const int ci = ct + cl;
            const float cp = cpL[cl];
            const size_t zrow = ((size_t)(b * CC + ci)) * NN;
            float s1 = 0.f, q1 = 0.f;
            #pragma unroll
            for (int nt = 0; nt < 4; ++nt) {
                const float val = acc[mt][nt][r] + cp;
                const int tok = n0 + nb + nt * 16 + lm;
                zbf[zrow + tok] = f2bf(val);
                s1 += val; q1 += val * val;
            }
            #pragma unroll
            for (int m = 1; m < 16; m <<= 1) {
                s1 += __shfl_xor(s1, m);
                q1 += __shfl_xor(q1, m);
            }
            if (lm == 0) { sSum[nbw][cl] = s1; sSq[nbw][cl] = q1; }
        }
    }
    __syncthreads();
    if (t < 128) {
        const int slot = blockIdx.z * 16 + blockIdx.x;
        statsPart[(size_t)slot * 512 + ct + t]       = sSum[0][t] + sSum[1][t];
        statsPart[(size_t)slot * 512 + 256 + ct + t] = sSq[0][t] + sSq[1][t];
    }
}

// ===========================================================================
// D5: finalize stats (4 blocks, coalesced row reads)
// ===========================================================================
__global__ __launch_bounds__(512) void bn_finalize(
    const float* __restrict__ statsPart, float* __restrict__ stats2)
{
    __shared__ float red[4][128];
    __shared__ float sf[128];
    const int g = blockIdx.x;                  // channels g*64 .. g*64+63
    const int t = threadIdx.x;
    const int cl = t & 127, sg = t >> 7;
    const int col = (cl < 64) ? (g * 64 + cl) : (256 + g * 64 + (cl - 64));
    float a = 0.f;
    for (int s = sg * 64; s < sg * 64 + 64; ++s)
        a += statsPart[(size_t)s * 512 + col];
    red[sg][cl] = a;
    __syncthreads();
    if (t < 128) sf[t] = red[0][t] + red[1][t] + red[2][t] + red[3][t];
    __syncthreads();
    if (t < 64) {
        const float cnt = (float)(BB * NN);
        const float mean = sf[t] / cnt;
        const float var = sf[64 + t] / cnt - mean * mean;
        const int c = g * 64 + t;
        stats2[c] = mean;
        stats2[CC + c] = rsqrtf(var + BN_EPS);
    }
}

// ===========================================================================
// D6: out = (z - mean)*istd*gamma + beta + x
// ===========================================================================
__global__ __launch_bounds__(256) void bn_apply(
    const ushort* __restrict__ zbf, const float* __restrict__ x,
    float* __restrict__ out, const float* __restrict__ stats2,
    const float* __restrict__ gamma, const float* __restrict__ beta)
{
    const size_t i = (size_t)blockIdx.x * 256 + threadIdx.x;
    const size_t base = i * 8;
    const int c = (int)((base >> 11) & (CC - 1));
    const float mean = stats2[c], istd = stats2[CC + c];
    const float gm = gamma[c] * istd;
    const float bt = beta[c] - mean * gm;
    const uint4 zz = *(const uint4*)(zbf + base);
    const float4 x0 = *(const float4*)(x + base);
    const float4 x1 = *(const float4*)(x + base + 4);
    float4 o0, o1;
    o0.x = bflo(zz.x) * gm + bt + x0.x;  o0.y = bfhi(zz.x) * gm + bt + x0.y;
    o0.z = bflo(zz.y) * gm + bt + x0.z;  o0.w = bfhi(zz.y) * gm + bt + x0.w;
    o1.x = bflo(zz.z) * gm + bt + x1.x;  o1.y = bfhi(zz.z) * gm + bt + x1.y;
    o1.z = bflo(zz.w) * gm + bt + x1.z;  o1.w = bfhi(zz.w) * gm + bt + x1.w;
    *(float4*)(out + base) = o0;
    *(float4*)(out + base + 4) = o1;
}

// ---------------------------------------------------------------------------
extern "C" void kernel_launch(void* const* d_in, const int* in_sizes, int n_in,
                              void* d_out, int out_size, void* d_ws, size_t ws_size,
                              hipStream_t stream) {
    const float* x    = (const float*)d_in[0];
    const float* g_w  = (const float*)d_in[1];
    const float* g_b  = (const float*)d_in[2];
    const float* th_w = (const float*)d_in[3];
    const float* th_b = (const float*)d_in[4];
    const float* ph_w = (const float*)d_in[5];
    const float* ph_b = (const float*)d_in[6];
    const float* W_w  = (const float*)d_in[7];
    // d_in[8] (W_b) cancels exactly in batch-norm
    const float* bn_g = (const float*)d_in[9];
    const float* bn_bt= (const float*)d_in[10];
    float* wsf = (float*)d_ws;
    float* out = (float*)d_out;
    ushort* ub = (ushort*)(wsf + OFF_FEND);

    mega1<<<dim3(545), 256, 0, stream>>>(
        x, W_w, g_w, ph_w, th_w, g_b, ph_b, th_b,
        wsf + OFF_GPART, wsf + OFF_SPART, ub + UXT,
        ub + UE, ub + UFT,
        wsf + OFF_PT, wsf + OFF_R1, wsf + OFF_WGB, wsf + OFF_ALPHA);
    mega2<<<dim3(1040), 256, 0, stream>>>(
        wsf + OFF_GPART, wsf + OFF_SPART, ub + UE, ub + UFT,
        wsf + OFF_PT, wsf + OFF_R1, wsf + OFF_WGB, wsf + OFF_ALPHA,
        ub + UGRAM, wsf + OFF_CP, wsf + OFF_L1, wsf + OFF_R2);
    sfused<<<dim3(64), 256, 0, stream>>>(
        ub + UE, ub + UGRAM, ub + UFT,
        wsf + OFF_R1, wsf + OFF_R2, wsf + OFF_L1, wsf + OFF_WGB, ub + USBF);
    z_mfma<<<dim3(16, 2, 16), 256, 0, stream>>>(
        ub + USBF, ub + UXT, wsf + OFF_CP, ub + UZ, wsf + OFF_STATP);
    bn_finalize<<<dim3(4), 512, 0, stream>>>(wsf + OFF_STATP, wsf + OFF_STAT2);
    bn_apply<<<dim3(4096), 256, 0, stream>>>(ub + UZ, x, out, wsf + OFF_STAT2, bn_g, bn_bt);
}

// Round 6
// 190.408 us; speedup vs baseline: 1.2140x; 1.2140x over previous
//
#include <hip/hip_runtime.h>

typedef unsigned int uint;
typedef unsigned short ushort;
typedef __attribute__((ext_vector_type(8))) short bf16x8;
typedef __attribute__((ext_vector_type(4))) float f32x4;

#define BB 16
#define CC 256
#define II 128
#define NN 2048
#define BN_EPS 1e-5f

// ---- float workspace offsets (all write-once, no zero-init) ----
#define OFF_GPART 0            // [4][16][256][256] = 4,194,304
#define OFF_SPART 4194304      // [4][16][256]      = 16,384
#define OFF_GPT   4210688      // [16][256]         = 4,096
#define OFF_CP    4214784      // [16][256]         = 4,096
#define OFF_STATP 4218880      // [256 slots][512]  = 131,072
#define OFF_STAT2 4349952      // [512]
#define OFF_PT    4350464      // [256]
#define OFF_R1    4350720      // [256]
#define OFF_WGB   4350976      // [256]
#define OFF_ALPHA 4351232      // [256] (only [0] used)
#define OFF_L1    4351488      // [16][256]
#define OFF_R2    4355584      // [16][256]
#define OFF_FEND  4359680
// ---- ushort offsets relative to (ushort*)(wsf + OFF_FEND) ----
#define UGRAM 0                // [16][256][256] bf16
#define UE    1048576          // [256][256]
#define UFT   1114112          // [256][256]
#define USBF  1179648          // [16][256][256]
#define UXT   2228224          // [16][2048][256]
#define UZ    10616832         // [16][256][2048]

static __device__ __forceinline__ ushort f2bf(float f) {
    uint u = __float_as_uint(f);
    return (ushort)((u + 0x7FFFu + ((u >> 16) & 1u)) >> 16);
}
static __device__ __forceinline__ uint pack2(float a, float b) {
    return (uint)f2bf(a) | ((uint)f2bf(b) << 16);
}
static __device__ __forceinline__ float bflo(uint w) { return __uint_as_float(w << 16); }
static __device__ __forceinline__ float bfhi(uint w) { return __uint_as_float(w & 0xFFFF0000u); }

#define MICRO_FMA(av, bv) \
    acc[0][0] += av.x * bv.x; acc[0][1] += av.x * bv.y; acc[0][2] += av.x * bv.z; acc[0][3] += av.x * bv.w; \
    acc[1][0] += av.y * bv.x; acc[1][1] += av.y * bv.y; acc[1][2] += av.y * bv.z; acc[1][3] += av.y * bv.w; \
    acc[2][0] += av.z * bv.x; acc[2][1] += av.z * bv.y; acc[2][2] += av.z * bv.z; acc[2][3] += av.z * bv.w; \
    acc[3][0] += av.w * bv.x; acc[3][1] += av.w * bv.y; acc[3][2] += av.w * bv.z; acc[3][3] += av.w * bv.w;

// ===========================================================================
// D1 mega1: blocks [0,256): Gram partials kc=4 (diag-dedup, diag emits xT)
//           blocks [256,289): weight precompute (E, FT, pt/r1/wgb/alpha)
// ===========================================================================
__global__ __launch_bounds__(256) void mega1(
    const float* __restrict__ x,
    const float* __restrict__ Ww, const float* __restrict__ Gw,
    const float* __restrict__ Pw, const float* __restrict__ Tw,
    const float* __restrict__ gb, const float* __restrict__ pb, const float* __restrict__ tb,
    float* __restrict__ gpart, float* __restrict__ sPart, ushort* __restrict__ xT,
    ushort* __restrict__ EBF, ushort* __restrict__ FT,
    float* __restrict__ pt, float* __restrict__ r1, float* __restrict__ wgb,
    float* __restrict__ alpha)
{
    __shared__ __align__(16) char smem[20480];
    const int bid = blockIdx.x;
    const int t = threadIdx.x;

    if (bid < 256) {
        // ---------------- Gram ----------------
        ushort (*As)[40] = (ushort(*)[40])smem;
        ushort (*Bs)[40] = (ushort(*)[40])(smem + 10240);
        const int jt = bid & 1, it = (bid >> 1) & 1;
        const int z = bid >> 2;               // 0..63
        const int b = z >> 2, kc = z & 3;
        const int iBase = it * 128, jBase = jt * 128;
        const bool diag = (it == jt);
        const int arow = t >> 1, ah = t & 1;
        const float* aSrc = x + ((size_t)(b * CC + iBase + arow)) * NN + kc * 512 + ah * 16;
        const float* bSrc = x + ((size_t)(b * CC + jBase + arow)) * NN + kc * 512 + ah * 16;
        const int lane = t & 63, wid = t >> 6;
        const int mb = (wid >> 1) * 64, nb = (wid & 1) * 64;
        const int lm = lane & 15, q = lane >> 4;
        f32x4 acc[4][4] = {};
        float ssum = 0.f;

        for (int it16 = 0; it16 < 16; ++it16) {
            const float4* ap = (const float4*)(aSrc + it16 * 32);
            float4 a0 = ap[0], a1 = ap[1], a2 = ap[2], a3 = ap[3];
            uint4 pa0 = { pack2(a0.x,a0.y), pack2(a0.z,a0.w), pack2(a1.x,a1.y), pack2(a1.z,a1.w) };
            uint4 pa1 = { pack2(a2.x,a2.y), pack2(a2.z,a2.w), pack2(a3.x,a3.y), pack2(a3.z,a3.w) };
            *(uint4*)&As[arow][ah * 16]     = pa0;
            *(uint4*)&As[arow][ah * 16 + 8] = pa1;
            if (!diag) {
                const float4* bp = (const float4*)(bSrc + it16 * 32);
                float4 b0 = bp[0], b1 = bp[1], b2 = bp[2], b3 = bp[3];
                uint4 pb0 = { pack2(b0.x,b0.y), pack2(b0.z,b0.w), pack2(b1.x,b1.y), pack2(b1.z,b1.w) };
                uint4 pb1 = { pack2(b2.x,b2.y), pack2(b2.z,b2.w), pack2(b3.x,b3.y), pack2(b3.z,b3.w) };
                *(uint4*)&Bs[arow][ah * 16]     = pb0;
                *(uint4*)&Bs[arow][ah * 16 + 8] = pb1;
            }
            if (jt == 0) {
                ssum += a0.x+a0.y+a0.z+a0.w + a1.x+a1.y+a1.z+a1.w
                      + a2.x+a2.y+a2.z+a2.w + a3.x+a3.y+a3.z+a3.w;
            }
            __syncthreads();
            const ushort (*Bsel)[40] = diag ? (const ushort(*)[40])As : (const ushort(*)[40])Bs;
            bf16x8 af[4], bf[4];
            #pragma unroll
            for (int mt = 0; mt < 4; ++mt)
                af[mt] = *(const bf16x8*)&As[mb + mt * 16 + lm][q * 8];
            #pragma unroll
            for (int nt = 0; nt < 4; ++nt)
                bf[nt] = *(const bf16x8*)&Bsel[nb + nt * 16 + lm][q * 8];
            #pragma unroll
            for (int mt = 0; mt < 4; ++mt)
                #pragma unroll
                for (int nt = 0; nt < 4; ++nt)
                    acc[mt][nt] = __builtin_amdgcn_mfma_f32_16x16x32_bf16(af[mt], bf[nt], acc[mt][nt], 0, 0, 0);
            if (diag) {
                // emit xT tile from As: As[c 128][n 32] -> xT[b][n][c]
                const int n_l = t & 31, cg = t >> 5;     // 8 groups x 16 channels
                uint qv[8];
                #pragma unroll
                for (int i2 = 0; i2 < 8; ++i2) {
                    ushort lo = As[cg * 16 + 2*i2][n_l];
                    ushort hi = As[cg * 16 + 2*i2 + 1][n_l];
                    qv[i2] = (uint)lo | ((uint)hi << 16);
                }
                const int ng = kc * 512 + it16 * 32 + n_l;
                uint4* op = (uint4*)(xT + ((size_t)(b * NN + ng)) * CC + iBase + cg * 16);
                op[0] = make_uint4(qv[0], qv[1], qv[2], qv[3]);
                op[1] = make_uint4(qv[4], qv[5], qv[6], qv[7]);
            }
            __syncthreads();
        }
        float* gp = gpart + ((size_t)kc * BB + b) * CC * CC;
        #pragma unroll
        for (int mt = 0; mt < 4; ++mt)
            #pragma unroll
            for (int nt = 0; nt < 4; ++nt)
                #pragma unroll
                for (int r = 0; r < 4; ++r) {
                    const int gi = iBase + mb + mt * 16 + q * 4 + r;
                    const int gj = jBase + nb + nt * 16 + lm;
                    gp[(size_t)gi * CC + gj] = acc[mt][nt][r];
                }
        if (jt == 0) {
            const float so = __shfl_xor(ssum, 1);
            if ((t & 1) == 0)
                sPart[((size_t)kc * BB + b) * CC + iBase + arow] = ssum + so;
        }
        return;
    }

    // ---------------- w1 ----------------
    const int bz = bid - 256;
    if (bz == 32) {
        float ptv = 0.f, r1v = 0.f, wgbv = 0.f;
        for (int d = 0; d < II; ++d) {
            ptv  += Pw[(size_t)d * CC + t] * tb[d];
            r1v  += Tw[(size_t)d * CC + t] * pb[d];
            wgbv += Ww[(size_t)t * II + d] * gb[d];
        }
        pt[t] = ptv; r1[t] = r1v; wgb[t] = wgbv;
        if (t == 0) {
            float al = 0.f;
            for (int d = 0; d < II; ++d) al += pb[d] * tb[d];
            alpha[0] = al;
        }
        return;
    }
    float (*As)[68] = (float(*)[68])smem;
    float (*Bs)[68] = (float(*)[68])(smem + 8704);
    const int a_r = t >> 2, a_k = (t & 3) * 8;
    const int b_n = t & 63, b_k = t >> 6;
    const int ty = t >> 4, tx = t & 15;
    float acc[4][4] = {};
    if (bz < 16) {
        // E[c][i] = sum_e Ww[c][e]*Gw[e][i]
        const int cBase = (bz >> 2) * 64, iBase = (bz & 3) * 64;
        const float* ap0 = Ww + (size_t)(cBase + a_r) * II + a_k;
        const float* bp0 = Gw + iBase + b_n;
        for (int k0 = 0; k0 < II; k0 += 32) {
            #pragma unroll
            for (int j = 0; j < 8; ++j) As[a_k + j][a_r] = ap0[k0 + j];
            #pragma unroll
            for (int kk = 0; kk < 8; ++kk) {
                const int k = b_k + kk * 4;
                Bs[k][b_n] = bp0[(size_t)(k0 + k) * CC];
            }
            __syncthreads();
            #pragma unroll
            for (int k = 0; k < 32; ++k) {
                const float4 av = *(const float4*)&As[k][ty * 4];
                const float4 bv = *(const float4*)&Bs[k][tx * 4];
                MICRO_FMA(av, bv)
            }
            __syncthreads();
        }
        #pragma unroll
        for (int ii = 0; ii < 4; ++ii) {
            uint2 o = { pack2(acc[ii][0], acc[ii][1]), pack2(acc[ii][2], acc[ii][3]) };
            *(uint2*)&EBF[(size_t)(cBase + ty * 4 + ii) * CC + iBase + tx * 4] = o;
        }
    } else {
        // FT[j][k] = (1/N) * sum_d Tw[d][j]*Pw[d][k]
        const int zz = bz - 16;
        const int jBase = (zz >> 2) * 64, kBase = (zz & 3) * 64;
        const float* ap0 = Tw + jBase + b_n;
        const float* bp0 = Pw + kBase + b_n;
        for (int k0 = 0; k0 < II; k0 += 32) {
            #pragma unroll
            for (int kk = 0; kk < 8; ++kk) {
                const int k = b_k + kk * 4;
                As[k][b_n] = ap0[(size_t)(k0 + k) * CC];
                Bs[k][b_n] = bp0[(size_t)(k0 + k) * CC];
            }
            __syncthreads();
            #pragma unroll
            for (int k = 0; k < 32; ++k) {
                const float4 av = *(const float4*)&As[k][ty * 4];
                const float4 bv = *(const float4*)&Bs[k][tx * 4];
                MICRO_FMA(av, bv)
            }
            __syncthreads();
        }
        const float sc = 1.0f / (float)NN;
        #pragma unroll
        for (int ii = 0; ii < 4; ++ii) {
            uint2 o = { pack2(acc[ii][0]*sc, acc[ii][1]*sc), pack2(acc[ii][2]*sc, acc[ii][3]*sc) };
            *(uint2*)&FT[(size_t)(jBase + ty * 4 + ii) * CC + kBase + tx * 4] = o;
        }
    }
}

// ===========================================================================
// D2 mega2: 1024 blocks. Each reduces 4 kc-partials for 4 complete Gram rows
// -> GramBF, AND computes Gpt[row] = Gram[row]·pt via wave shfl (1 row = 1 wave).
// ===========================================================================
__global__ __launch_bounds__(256) void mega2(
    const float* __restrict__ gpart, const float* __restrict__ pt,
    ushort* __restrict__ GramBF, float* __restrict__ Gpt)
{
    __shared__ float ptL[256];
    const int bid = blockIdx.x;
    const int t = threadIdx.x;
    const int i = bid * 256 + t;               // float4 idx, 0..262143
    const size_t S = (size_t)BB * CC * CC / 4;
    const float4* p = (const float4*)gpart;
    float4 v0 = p[i], v1 = p[i + S], v2 = p[i + 2 * S], v3 = p[i + 3 * S];
    if (t < 256) ptL[t] = pt[t];
    float4 o = { v0.x + v1.x + v2.x + v3.x, v0.y + v1.y + v2.y + v3.y,
                 v0.z + v1.z + v2.z + v3.z, v0.w + v1.w + v2.w + v3.w };
    uint2 pk = { pack2(o.x, o.y), pack2(o.z, o.w) };
    ((uint2*)GramBF)[i] = pk;
    __syncthreads();
    const int lane = t & 63;
    float dot = o.x * ptL[lane * 4] + o.y * ptL[lane * 4 + 1]
              + o.z * ptL[lane * 4 + 2] + o.w * ptL[lane * 4 + 3];
    #pragma unroll
    for (int m = 32; m > 0; m >>= 1) dot += __shfl_xor(dot, m);
    if (lane == 0) {
        const int row = bid * 4 + (t >> 6);    // global row in [0, 16*256)
        Gpt[row] = dot;
    }
}

// ===========================================================================
// D3 u_kernel: 16 blocks: cprime, L1, R2 from tiny inputs
// ===========================================================================
__global__ __launch_bounds__(256) void u_kernel(
    const float* __restrict__ sPart, const float* __restrict__ Gpt,
    const ushort* __restrict__ EBF, const ushort* __restrict__ FT,
    const float* __restrict__ pt, const float* __restrict__ r1,
    const float* __restrict__ wgb, const float* __restrict__ alpha,
    float* __restrict__ cprime, float* __restrict__ L1, float* __restrict__ R2)
{
    const int b = blockIdx.x, t = threadIdx.x;
    __shared__ __align__(16) float sL[256], GptL[256], red[256];
    {
        float s = 0.f;
        #pragma unroll
        for (int kc = 0; kc < 4; ++kc) s += sPart[((size_t)kc * BB + b) * CC + t];
        sL[t] = s;
        GptL[t] = Gpt[b * CC + t];
        red[t] = s * pt[t];
    }
    __syncthreads();
    for (int s = 128; s > 0; s >>= 1) {
        if (t < s) red[t] += red[t + s];
        __syncthreads();
    }
    const float spt = red[0];
    float es = 0.f, eg = 0.f;
    {
        const uint4* ep = (const uint4*)(EBF + (size_t)t * CC);
        #pragma unroll 4
        for (int kk = 0; kk < 32; ++kk) {
            uint4 v = ep[kk]; const int k = kk * 8;
            float e0=bflo(v.x),e1=bfhi(v.x),e2=bflo(v.y),e3=bfhi(v.y);
            float e4=bflo(v.z),e5=bfhi(v.z),e6=bflo(v.w),e7=bfhi(v.w);
            es += e0*sL[k]+e1*sL[k+1]+e2*sL[k+2]+e3*sL[k+3]+e4*sL[k+4]+e5*sL[k+5]+e6*sL[k+6]+e7*sL[k+7];
            eg += e0*GptL[k]+e1*GptL[k+1]+e2*GptL[k+2]+e3*GptL[k+3]+e4*GptL[k+4]+e5*GptL[k+5]+e6*GptL[k+6]+e7*GptL[k+7];
        }
    }
    float r2 = 0.f;
    {
        const uint4* fp = (const uint4*)(FT + (size_t)t * CC);
        #pragma unroll 4
        for (int kk = 0; kk < 32; ++kk) {
            uint4 v = fp[kk]; const int k = kk * 8;
            r2 += bflo(v.x)*sL[k]   + bfhi(v.x)*sL[k+1] + bflo(v.y)*sL[k+2] + bfhi(v.y)*sL[k+3]
                + bflo(v.z)*sL[k+4] + bfhi(v.z)*sL[k+5] + bflo(v.w)*sL[k+6] + bfhi(v.w)*sL[k+7];
        }
    }
    const float al = alpha[0];
    const float wg = wgb[t];
    cprime[b * CC + t] = (eg + al * es + spt * wg) / (float)NN + al * wg;
    L1[b * CC + t] = es / (float)NN;
    R2[b * CC + t] = r2 + r1[t];
}

// ===========================================================================
// D4 sfused: stage1 Q = E x Gram_b -> LDS; stage2 S = Q x FT^T + rank-1 -> Sbf
// ===========================================================================
__global__ __launch_bounds__(256) void sfused(
    const ushort* __restrict__ EBF, const ushort* __restrict__ GramBF,
    const ushort* __restrict__ FT,
    const float* __restrict__ r1, const float* __restrict__ R2,
    const float* __restrict__ L1, const float* __restrict__ wgb,
    ushort* __restrict__ Sbf)
{
    __shared__ ushort As[128][40];
    __shared__ ushort Bs[128][40];
    __shared__ ushort Qs[128][264];
    const int t = threadIdx.x;
    const int b = blockIdx.x >> 2;
    const int ct = (blockIdx.x >> 1) & 1, jt = blockIdx.x & 1;
    const int cBase = ct * 128, jBase = jt * 128;
    const int arow = t >> 1, ah = t & 1;
    const int lane = t & 63, wid = t >> 6;
    const int mb = (wid >> 1) * 64, nb = (wid & 1) * 64;
    const int lm = lane & 15, q = lane >> 4;
    const ushort* aSrc = EBF + (size_t)(cBase + arow) * CC + ah * 16;

    #pragma unroll
    for (int half = 0; half < 2; ++half) {
        const ushort* bSrc = GramBF + ((size_t)b * CC + half * 128 + arow) * CC + ah * 16;
        f32x4 acc[4][4] = {};
        for (int k0 = 0; k0 < CC; k0 += 32) {
            *(uint4*)&As[arow][ah * 16]     = ((const uint4*)(aSrc + k0))[0];
            *(uint4*)&As[arow][ah * 16 + 8] = ((const uint4*)(aSrc + k0))[1];
            *(uint4*)&Bs[arow][ah * 16]     = ((const uint4*)(bSrc + k0))[0];
            *(uint4*)&Bs[arow][ah * 16 + 8] = ((const uint4*)(bSrc + k0))[1];
            __syncthreads();
            bf16x8 af[4], bf[4];
            #pragma unroll
            for (int mt = 0; mt < 4; ++mt)
                af[mt] = *(const bf16x8*)&As[mb + mt * 16 + lm][q * 8];
            #pragma unroll
            for (int nt = 0; nt < 4; ++nt)
                bf[nt] = *(const bf16x8*)&Bs[nb + nt * 16 + lm][q * 8];
            #pragma unroll
            for (int mt = 0; mt < 4; ++mt)
                #pragma unroll
                for (int nt = 0; nt < 4; ++nt)
                    acc[mt][nt] = __builtin_amdgcn_mfma_f32_16x16x32_bf16(af[mt], bf[nt], acc[mt][nt], 0, 0, 0);
            __syncthreads();
        }
        #pragma unroll
        for (int mt = 0; mt < 4; ++mt)
            #pragma unroll
            for (int nt = 0; nt < 4; ++nt)
                #pragma unroll
                for (int r = 0; r < 4; ++r)
                    Qs[mb + mt * 16 + q * 4 + r][half * 128 + nb + nt * 16 + lm] = f2bf(acc[mt][nt][r]);
        __syncthreads();
    }
    // stage 2
    f32x4 acc[4][4] = {};
    const ushort* fSrc = FT + (size_t)(jBase + arow) * CC + ah * 16;
    for (int k0 = 0; k0 < CC; k0 += 32) {
        *(uint4*)&Bs[arow][ah * 16]     = ((const uint4*)(fSrc + k0))[0];
        *(uint4*)&Bs[arow][ah * 16 + 8] = ((const uint4*)(fSrc + k0))[1];
        __syncthreads();
        bf16x8 af[4], bf[4];
        #pragma unroll
        for (int mt = 0; mt < 4; ++mt)
            af[mt] = *(const bf16x8*)&Qs[mb + mt * 16 + lm][k0 + q * 8];
        #pragma unroll
        for (int nt = 0; nt < 4; ++nt)
            bf[nt] = *(const bf16x8*)&Bs[nb + nt * 16 + lm][q * 8];
        #pragma unroll
        for (int mt = 0; mt < 4; ++mt)
            #pragma unroll
            for (int nt = 0; nt < 4; ++nt)
                acc[mt][nt] = __builtin_amdgcn_mfma_f32_16x16x32_bf16(af[mt], bf[nt], acc[mt][nt], 0, 0, 0);
        __syncthreads();
    }
    float r1v[4], R2v[4];
    #pragma unroll
    for (int nt = 0; nt < 4; ++nt) {
        const int j = jBase + nb + nt * 16 + lm;
        r1v[nt] = r1[j];
        R2v[nt] = R2[b * CC + j];
    }
    ushort* dst = Sbf + (size_t)b * CC * CC;
    #pragma unroll
    for (int mt = 0; mt < 4; ++mt)
        #pragma unroll
        for (int r = 0; r < 4; ++r) {
            const int c = cBase + mb + mt * 16 + q * 4 + r;
            const float l1v = L1[b * CC + c], wgv = wgb[c];
            #pragma unroll
            for (int nt = 0; nt < 4; ++nt) {
                const int j = jBase + nb + nt * 16 + lm;
                dst[(size_t)c * CC + j] = f2bf(acc[mt][nt][r] + l1v * r1v[nt] + wgv * R2v[nt]);
            }
        }
}

// ===========================================================================
// D5: z_b = S_b @ x_b + c' 1^T (bf16 MFMA) -> zbf; per-block BN partials
// ===========================================================================
__global__ __launch_bounds__(256) void z_mfma(
    const ushort* __restrict__ Sbf, const ushort* __restrict__ xT,
    const float* __restrict__ cprime, ushort* __restrict__ zbf,
    float* __restrict__ statsPart)
{
    __shared__ ushort As[128][40];
    __shared__ ushort Bs[128][40];
    __shared__ float cpL[128];
    __shared__ float sSum[2][128], sSq[2][128];
    const int t = threadIdx.x;
    const int n0 = blockIdx.x * 128, ct = blockIdx.y * 128, b = blockIdx.z;
    const int arow = t >> 1, ah = t & 1;
    const ushort* aSrc = Sbf + ((size_t)(b * CC + ct + arow)) * CC + ah * 16;
    const ushort* bSrc = xT + ((size_t)(b * NN + n0 + arow)) * CC + ah * 16;
    const int lane = t & 63, wid = t >> 6;
    const int mb = (wid >> 1) * 64, nb = (wid & 1) * 64;
    const int lm = lane & 15, q = lane >> 4;
    f32x4 acc[4][4] = {};

    if (t < 128) cpL[t] = cprime[b * CC + ct + t];

    for (int k0 = 0; k0 < CC; k0 += 32) {
        *(uint4*)&As[arow][ah * 16]     = ((const uint4*)(aSrc + k0))[0];
        *(uint4*)&As[arow][ah * 16 + 8] = ((const uint4*)(aSrc + k0))[1];
        *(uint4*)&Bs[arow][ah * 16]     = ((const uint4*)(bSrc + k0))[0];
        *(uint4*)&Bs[arow][ah * 16 + 8] = ((const uint4*)(bSrc + k0))[1];
        __syncthreads();
        bf16x8 af[4], bf[4];
        #pragma unroll
        for (int mt = 0; mt < 4; ++mt)
            af[mt] = *(const bf16x8*)&As[mb + mt * 16 + lm][q * 8];
        #pragma unroll
        for (int nt = 0; nt < 4; ++nt)
            bf[nt] = *(const bf16x8*)&Bs[nb + nt * 16 + lm][q * 8];
        #pragma unroll
        for (int mt = 0; mt < 4; ++mt)
            #pragma unroll
            for (int nt = 0; nt < 4; ++nt)
                acc[mt][nt] = __builtin_amdgcn_mfma_f32_16x16x32_bf16(af[mt], bf[nt], acc[mt][nt], 0, 0, 0);
        __syncthreads();
    }
    const int nbw = wid & 1;
    #pragma unroll
    for (int mt = 0; mt < 4; ++mt) {
        #pragma unroll
        for (int r = 0; r < 4; ++r) {
            const int cl = mb + mt * 16 + q * 4 + r;
            const int ci = ct + cl;
            const float cp = cpL[cl];
            const size_t zrow = ((size_t)(b * CC + ci)) * NN;
            float s1 = 0.f, q1 = 0.f;
            #pragma unroll
            for (int nt = 0; nt < 4; ++nt) {
                const float val = acc[mt][nt][r] + cp;
                const int tok = n0 + nb + nt * 16 + lm;
                zbf[zrow + tok] = f2bf(val);
                s1 += val; q1 += val * val;
            }
            #pragma unroll
            for (int m = 1; m < 16; m <<= 1) {
                s1 += __shfl_xor(s1, m);
                q1 += __shfl_xor(q1, m);
            }
            if (lm == 0) { sSum[nbw][cl] = s1; sSq[nbw][cl] = q1; }
        }
    }
    __syncthreads();
    if (t < 128) {
        const int slot = blockIdx.z * 16 + blockIdx.x;
        statsPart[(size_t)slot * 512 + ct + t]       = sSum[0][t] + sSum[1][t];
        statsPart[(size_t)slot * 512 + 256 + ct + t] = sSq[0][t] + sSq[1][t];
    }
}

// ===========================================================================
// D6: finalize stats (4 blocks, coalesced row reads)
// ===========================================================================
__global__ __launch_bounds__(512) void bn_finalize(
    const float* __restrict__ statsPart, float* __restrict__ stats2)
{
    __shared__ float red[4][128];
    __shared__ float sf[128];
    const int g = blockIdx.x;                  // channels g*64 .. g*64+63
    const int t = threadIdx.x;
    const int cl = t & 127, sg = t >> 7;
    const int col = (cl < 64) ? (g * 64 + cl) : (256 + g * 64 + (cl - 64));
    float a = 0.f;
    for (int s = sg * 64; s < sg * 64 + 64; ++s)
        a += statsPart[(size_t)s * 512 + col];
    red[sg][cl] = a;
    __syncthreads();
    if (t < 128) sf[t] = red[0][t] + red[1][t] + red[2][t] + red[3][t];
    __syncthreads();
    if (t < 64) {
        const float cnt = (float)(BB * NN);
        const float mean = sf[t] / cnt;
        const float var = sf[64 + t] / cnt - mean * mean;
        const int c = g * 64 + t;
        stats2[c] = mean;
        stats2[CC + c] = rsqrtf(var + BN_EPS);
    }
}

// ===========================================================================
// D7: out = (z - mean)*istd*gamma + beta + x
// ===========================================================================
__global__ __launch_bounds__(256) void bn_apply(
    const ushort* __restrict__ zbf, const float* __restrict__ x,
    float* __restrict__ out, const float* __restrict__ stats2,
    const float* __restrict__ gamma, const float* __restrict__ beta)
{
    const size_t i = (size_t)blockIdx.x * 256 + threadIdx.x;
    const size_t base = i * 8;
    const int c = (int)((base >> 11) & (CC - 1));
    const float mean = stats2[c], istd = stats2[CC + c];
    const float gm = gamma[c] * istd;
    const float bt = beta[c] - mean * gm;
    const uint4 zz = *(const uint4*)(zbf + base);
    const float4 x0 = *(const float4*)(x + base);
    const float4 x1 = *(const float4*)(x + base + 4);
    float4 o0, o1;
    o0.x = bflo(zz.x) * gm + bt + x0.x;  o0.y = bfhi(zz.x) * gm + bt + x0.y;
    o0.z = bflo(zz.y) * gm + bt + x0.z;  o0.w = bfhi(zz.y) * gm + bt + x0.w;
    o1.x = bflo(zz.z) * gm + bt + x1.x;  o1.y = bfhi(zz.z) * gm + bt + x1.y;
    o1.z = bflo(zz.w) * gm + bt + x1.z;  o1.w = bfhi(zz.w) * gm + bt + x1.w;
    *(float4*)(out + base) = o0;
    *(float4*)(out + base + 4) = o1;
}

// ---------------------------------------------------------------------------
extern "C" void kernel_launch(void* const* d_in, const int* in_sizes, int n_in,
                              void* d_out, int out_size, void* d_ws, size_t ws_size,
                              hipStream_t stream) {
    const float* x    = (const float*)d_in[0];
    const float* g_w  = (const float*)d_in[1];
    const float* g_b  = (const float*)d_in[2];
    const float* th_w = (const float*)d_in[3];
    const float* th_b = (const float*)d_in[4];
    const float* ph_w = (const float*)d_in[5];
    const float* ph_b = (const float*)d_in[6];
    const float* W_w  = (const float*)d_in[7];
    // d_in[8] (W_b) cancels exactly in batch-norm
    const float* bn_g = (const float*)d_in[9];
    const float* bn_bt= (const float*)d_in[10];
    float* wsf = (float*)d_ws;
    float* out = (float*)d_out;
    ushort* ub = (ushort*)(wsf + OFF_FEND);

    mega1<<<dim3(289), 256, 0, stream>>>(
        x, W_w, g_w, ph_w, th_w, g_b, ph_b, th_b,
        wsf + OFF_GPART, wsf + OFF_SPART, ub + UXT,
        ub + UE, ub + UFT,
        wsf + OFF_PT, wsf + OFF_R1, wsf + OFF_WGB, wsf + OFF_ALPHA);
    mega2<<<dim3(1024), 256, 0, stream>>>(
        wsf + OFF_GPART, wsf + OFF_PT, ub + UGRAM, wsf + OFF_GPT);
    u_kernel<<<dim3(16), 256, 0, stream>>>(
        wsf + OFF_SPART, wsf + OFF_GPT, ub + UE, ub + UFT,
        wsf + OFF_PT, wsf + OFF_R1, wsf + OFF_WGB, wsf + OFF_ALPHA,
        wsf + OFF_CP, wsf + OFF_L1, wsf + OFF_R2);
    sfused<<<dim3(64), 256, 0, stream>>>(
        ub + UE, ub + UGRAM, ub + UFT,
        wsf + OFF_R1, wsf + OFF_R2, wsf + OFF_L1, wsf + OFF_WGB, ub + USBF);
    z_mfma<<<dim3(16, 2, 16), 256, 0, stream>>>(
        ub + USBF, ub + UXT, wsf + OFF_CP, ub + UZ, wsf + OFF_STATP);
    bn_finalize<<<dim3(4), 512, 0, stream>>>(wsf + OFF_STATP, wsf + OFF_STAT2);
    bn_apply<<<dim3(4096), 256, 0, stream>>>(ub + UZ, x, out, wsf + OFF_STAT2, bn_g, bn_bt);
}